// Round 9
// baseline (355.117 us; speedup 1.0000x reference)
//
#include <hip/hip_runtime.h>
#include <hip/hip_fp16.h>
#include <hip/hip_fp8.h>

#define NUM_TEAMS 100000
#define EMBED     32
#define N_EDGES   2000000
#define BQ        524288
#define TARGET_DIM 3

// ---- bucket partition parameters ----
#define BSH    9
#define BSPAN  512
#define NBUCK  ((NUM_TEAMS + BSPAN - 1) / BSPAN)   // 196
#define TILE   8192
#define P2_BLOCKS ((N_EDGES + TILE - 1) / TILE)    // 245

// ---------------- P1: bucket histogram ----------------
__global__ void __launch_bounds__(256) bhist_kernel(const int* __restrict__ dst,
                                                    int* __restrict__ bhist, int n) {
    __shared__ int cnt[NBUCK];
    int t = threadIdx.x;
    for (int i = t; i < NBUCK; i += 256) cnt[i] = 0;
    __syncthreads();
    int base = blockIdx.x * TILE;
    for (int j = 0; j < TILE; j += 256) {
        int i = base + j + t;
        if (i < n) atomicAdd(&cnt[dst[i] >> BSH], 1);
    }
    __syncthreads();
    for (int i = t; i < NBUCK; i += 256) if (cnt[i]) atomicAdd(&bhist[i], cnt[i]);
}

// ---------------- P1b: scan bucket counts (1 block) ----------------
__global__ void __launch_bounds__(256) bscan_kernel(const int* __restrict__ bhist,
                                                    int* __restrict__ bbase,
                                                    int* __restrict__ bcursor,
                                                    int* __restrict__ row_ptr) {
    __shared__ int wsum[4];
    int t = threadIdx.x;
    int v = (t < NBUCK) ? bhist[t] : 0;
    int lane = t & 63, wid = t >> 6;
    int incl = v;
    #pragma unroll
    for (int off = 1; off < 64; off <<= 1) {
        int u = __shfl_up(incl, off, 64);
        if (lane >= off) incl += u;
    }
    if (lane == 63) wsum[wid] = incl;
    __syncthreads();
    int wofs = 0;
    for (int w = 0; w < wid; ++w) wofs += wsum[w];
    int excl = incl - v + wofs;
    if (t < NBUCK) { bbase[t] = excl; bcursor[t] = excl; }
    if (t == 0) { bbase[NBUCK] = N_EDGES; row_ptr[NUM_TEAMS] = N_EDGES; }
}

// ---------------- P2: chunked partition into bucket regions ----------------
__global__ void __launch_bounds__(256) partition_kernel(
        const int* __restrict__ src, const int* __restrict__ dst,
        const float* __restrict__ ew,
        int* __restrict__ bcursor, int2* __restrict__ recs, int n) {
    __shared__ int cnt[NBUCK];
    __shared__ int lbase[NBUCK];
    int t = threadIdx.x;
    for (int i = t; i < NBUCK; i += 256) cnt[i] = 0;
    __syncthreads();
    int base = blockIdx.x * TILE;
    for (int j = 0; j < TILE; j += 256) {
        int i = base + j + t;
        if (i < n) atomicAdd(&cnt[dst[i] >> BSH], 1);
    }
    __syncthreads();
    for (int b = t; b < NBUCK; b += 256) {
        int c = cnt[b];
        lbase[b] = c ? atomicAdd(&bcursor[b], c) : 0;
        cnt[b] = 0;
    }
    __syncthreads();
    for (int j = 0; j < TILE; j += 256) {
        int i = base + j + t;
        if (i < n) {
            int d = dst[i];
            int b = d >> BSH;
            int r = atomicAdd(&cnt[b], 1);
            int2 rec;
            rec.x = src[i] | ((d & (BSPAN - 1)) << 17);
            rec.y = __float_as_int(ew[i]);
            recs[lbase[b] + r] = rec;
        }
    }
}

// ---------------- P3: per-bucket CSR finalize ----------------
__global__ void __launch_bounds__(256) finalize_kernel(
        const int2* __restrict__ recs, const int* __restrict__ bbase,
        int* __restrict__ row_ptr, int2* __restrict__ epack) {
    __shared__ int cnt[BSPAN];
    __shared__ int excl[BSPAN];
    int b = blockIdx.x;
    int t = threadIdx.x;
    int rbase = bbase[b], rend = bbase[b + 1];
    for (int i = t; i < BSPAN; i += 256) cnt[i] = 0;
    __syncthreads();
    for (int k = rbase + t; k < rend; k += 256)
        atomicAdd(&cnt[recs[k].x >> 17], 1);
    __syncthreads();
    if (t < 64) {
        int c[8]; int s = 0;
        #pragma unroll
        for (int k = 0; k < 8; ++k) { c[k] = cnt[t * 8 + k]; s += c[k]; }
        int incl = s;
        #pragma unroll
        for (int off = 1; off < 64; off <<= 1) {
            int u = __shfl_up(incl, off, 64);
            if (t >= off) incl += u;
        }
        int e = incl - s;
        #pragma unroll
        for (int k = 0; k < 8; ++k) { excl[t * 8 + k] = e; e += c[k]; }
    }
    __syncthreads();
    for (int i = t; i < BSPAN; i += 256) {
        int node = b * BSPAN + i;
        if (node < NUM_TEAMS) row_ptr[node] = rbase + excl[i];
        cnt[i] = excl[i];
    }
    __syncthreads();
    for (int k = rbase + t; k < rend; k += 256) {
        int2 rec = recs[k];
        int dloc = rec.x >> 17;
        int r = atomicAdd(&cnt[dloc], 1);
        int2 e; e.x = rec.x & 0x1FFFF; e.y = rec.y;
        epack[rbase + r] = e;
    }
}

// ---------------- f32 -> fp16 + fp8 convert ----------------
__global__ void __launch_bounds__(256) cvt_kernel(const float* __restrict__ in,
                                                  __half* __restrict__ out16,
                                                  __hip_fp8x2_storage_t* __restrict__ out8,
                                                  int n2) {
    int i = blockIdx.x * 256 + threadIdx.x;
    if (i < n2) {
        float2 v = *(const float2*)(in + 2 * i);
        *(__half2*)(out16 + 2 * i) = __floats2half2_rn(v.x, v.y);
        __hip_fp8x2_e4m3 q(v);
        out8[i] = q.__x;
    }
}

// ---------------- fused GraphConv (16 lanes/node, half2 lanes) ----------------
// Gather path reads the fp8-e4m3 table (3.2MB, L2-resident); root/transform fp16/f32.
#define CONV_NPB 16
__global__ void __launch_bounds__(256) conv_kernel(
        const __half* __restrict__ xh,                     // fp16 x (root path)
        const __hip_fp8x2_storage_t* __restrict__ x8,      // fp8 x (gather path), 16/node
        const int* __restrict__ row_ptr,
        const int2* __restrict__ epack,
        const float* __restrict__ w_rel,   // [32][32] row-major
        const float* __restrict__ b_rel,   // [32]
        const float* __restrict__ w_root,  // [32][32]
        __half* __restrict__ x_out,                        // nullable
        __hip_fp8x2_storage_t* __restrict__ x8_out,        // nullable
        const float* __restrict__ w0,      // [8][64], nullable
        __half* __restrict__ uv_out) {     // [NUM_TEAMS][16], nullable
    __shared__ float s_wrelT[32 * 33];
    __shared__ float s_wrootT[32 * 33];
    __shared__ float s_b[32];
    __shared__ float s_agg[CONV_NPB][33];   // odd stride + scalar stores: 2-way max (free)
    __shared__ float s_x[CONV_NPB][33];
    __shared__ float s_o[CONV_NPB][33];
    __shared__ float s_w0[8 * 66];

    int t = threadIdx.x;
    for (int i = t; i < 1024; i += 256) {
        int j = i >> 5, d = i & 31;
        s_wrelT[d * 33 + j]  = w_rel[i];
        s_wrootT[d * 33 + j] = w_root[i];
    }
    if (t < 32) s_b[t] = b_rel[t];
    if (w0) {
        for (int i = t; i < 512; i += 256)
            s_w0[(i >> 6) * 66 + (i & 63)] = w0[i];
    }

    int ln = t >> 4;           // node within block
    int l  = t & 15;           // dim-pair index
    int node = blockIdx.x * CONV_NPB + ln;   // 100000 = 6250*16 exact

    const __half2* xh2 = (const __half2*)xh;
    float2 xv = __half22float2(xh2[node * 16 + l]);
    int r0 = row_ptr[node], r1 = row_ptr[node + 1];
    int lim = r1 - 1;

    __half2 acc[8];
    #pragma unroll
    for (int j = 0; j < 8; ++j) acc[j] = __floats2half2_rn(0.f, 0.f);

    for (int k = r0; k < r1; k += 8) {
        int sx[8]; float wv[8];
        #pragma unroll
        for (int j = 0; j < 8; ++j) {
            int idx = k + j;
            idx = idx < lim ? idx : lim;
            long long raw = __builtin_nontemporal_load(
                                (const long long*)(epack + idx));
            sx[j] = (int)(unsigned)(raw & 0xffffffffll);
            wv[j] = __int_as_float((int)(raw >> 32));
        }
        __hip_fp8x2_storage_t r8[8];
        #pragma unroll
        for (int j = 0; j < 8; ++j) r8[j] = x8[sx[j] * 16 + l];
        #pragma unroll
        for (int j = 0; j < 8; ++j) {
            float w = (k + j <= lim) ? wv[j] : 0.f;
            __half2 w2 = __floats2half2_rn(w, w);
            __hip_fp8x2_e4m3 p; p.__x = r8[j];
            __half2 g = (__half2)p;
            acc[j] = __hfma2(w2, g, acc[j]);
        }
    }
    float2 a = {0.f, 0.f};
    #pragma unroll
    for (int j = 0; j < 8; ++j) {
        float2 f = __half22float2(acc[j]);
        a.x += f.x; a.y += f.y;
    }
    s_agg[ln][2 * l]     = a.x;
    s_agg[ln][2 * l + 1] = a.y;
    s_x[ln][2 * l]       = xv.x;
    s_x[ln][2 * l + 1]   = xv.y;
    __syncthreads();

    int j0 = 2 * l, j1 = 2 * l + 1;
    float o0 = s_b[j0], o1 = s_b[j1];
    #pragma unroll
    for (int d = 0; d < 32; ++d) {
        float ag = s_agg[ln][d];
        float xx = s_x[ln][d];
        o0 += s_wrelT[d * 33 + j0] * ag + s_wrootT[d * 33 + j0] * xx;
        o1 += s_wrelT[d * 33 + j1] * ag + s_wrootT[d * 33 + j1] * xx;
    }
    o0 = (o0 >= 0.f) ? o0 : 0.01f * o0;
    o1 = (o1 >= 0.f) ? o1 : 0.01f * o1;
    if (x_out)
        ((__half2*)x_out)[node * 16 + l] = __floats2half2_rn(o0, o1);
    if (x8_out) {
        __hip_fp8x2_e4m3 q(make_float2(o0, o1));
        x8_out[node * 16 + l] = q.__x;
    }

    if (uv_out) {
        s_o[ln][2 * l]     = o0;
        s_o[ln][2 * l + 1] = o1;
        __syncthreads();
        const float* wrow = (l < 8) ? (s_w0 + l * 66) : (s_w0 + (l - 8) * 66 + 32);
        float uvv = 0.f;
        #pragma unroll
        for (int d = 0; d < 32; ++d) uvv += wrow[d] * s_o[ln][d];
        uv_out[node * 16 + l] = __float2half(uvv);
    }
}

// ---------------- final pair MLP (layers 1-4) + log_softmax ----------------
__global__ void __launch_bounds__(256) mlp_kernel(
        const __half* __restrict__ uv,
        const int* __restrict__ home, const int* __restrict__ away,
        const float* __restrict__ b0,
        const float* __restrict__ w1, const float* __restrict__ b1,
        const float* __restrict__ w2, const float* __restrict__ b2,
        const float* __restrict__ w3, const float* __restrict__ b3,
        const float* __restrict__ w4, const float* __restrict__ b4,
        float* __restrict__ out, int n) {
    __shared__ float s_w1[64], s_w2[64], s_w3[64], s_w4[24];
    __shared__ float s_b0[8], s_b1[8], s_b2[8], s_b3[8], s_b4[3];
    int t = threadIdx.x;
    if (t < 64) { s_w1[t] = w1[t]; s_w2[t] = w2[t]; s_w3[t] = w3[t]; }
    if (t < 24) s_w4[t] = w4[t];
    if (t < 8)  { s_b0[t] = b0[t]; s_b1[t] = b1[t]; s_b2[t] = b2[t]; s_b3[t] = b3[t]; }
    if (t < 3)  s_b4[t] = b4[t];
    __syncthreads();

    int i = blockIdx.x * 256 + t;
    if (i >= n) return;

    int hi = __builtin_nontemporal_load(home + i);
    int ai = __builtin_nontemporal_load(away + i);

    const __half2* pu = (const __half2*)(uv + (size_t)hi * 16);
    const __half2* pv = (const __half2*)(uv + (size_t)ai * 16 + 8);

    float h1[8];
    #pragma unroll
    for (int q = 0; q < 4; ++q) {
        float2 fu = __half22float2(pu[q]);
        float2 fv = __half22float2(pv[q]);
        float o0 = fu.x + fv.x + s_b0[2 * q];
        float o1 = fu.y + fv.y + s_b0[2 * q + 1];
        h1[2 * q]     = (o0 >= 0.f) ? o0 : 0.01f * o0;
        h1[2 * q + 1] = (o1 >= 0.f) ? o1 : 0.01f * o1;
    }

    float h2[8];
    #pragma unroll
    for (int j = 0; j < 8; ++j) {
        float o = s_b1[j];
        #pragma unroll
        for (int d = 0; d < 8; ++d) o += s_w1[j * 8 + d] * h1[d];
        h2[j] = (o >= 0.f) ? o : 0.01f * o;
    }
    float h3[8];
    #pragma unroll
    for (int j = 0; j < 8; ++j) {
        float o = s_b2[j];
        #pragma unroll
        for (int d = 0; d < 8; ++d) o += s_w2[j * 8 + d] * h2[d];
        h3[j] = (o >= 0.f) ? o : 0.01f * o;
    }
    float h4[8];
    #pragma unroll
    for (int j = 0; j < 8; ++j) {
        float o = s_b3[j];
        #pragma unroll
        for (int d = 0; d < 8; ++d) o += s_w3[j * 8 + d] * h3[d];
        h4[j] = (o >= 0.f) ? o : 0.01f * o;
    }
    float f[3];
    #pragma unroll
    for (int j = 0; j < 3; ++j) {
        float o = s_b4[j];
        #pragma unroll
        for (int d = 0; d < 8; ++d) o += s_w4[j * 8 + d] * h4[d];
        f[j] = (o >= 0.f) ? o : 0.01f * o;
    }
    float m  = fmaxf(f[0], fmaxf(f[1], f[2]));
    float s  = expf(f[0] - m) + expf(f[1] - m) + expf(f[2] - m);
    float ls = logf(s);
    out[3 * i + 0] = f[0] - m - ls;
    out[3 * i + 1] = f[1] - m - ls;
    out[3 * i + 2] = f[2] - m - ls;
}

// ---------------- launch ----------------

extern "C" void kernel_launch(void* const* d_in, const int* in_sizes, int n_in,
                              void* d_out, int out_size, void* d_ws, size_t ws_size,
                              hipStream_t stream) {
    const int*   edge_index = (const int*)d_in[0];
    const int*   src   = edge_index;
    const int*   dst   = edge_index + N_EDGES;
    const float* ew    = (const float*)d_in[1];
    const int*   home  = (const int*)d_in[2];
    const int*   away  = (const int*)d_in[3];
    const float* embed = (const float*)d_in[4];
    const float* w_rel  = (const float*)d_in[5];
    const float* b_rel  = (const float*)d_in[6];
    const float* w_root = (const float*)d_in[7];
    const float* w0 = (const float*)d_in[8];  const float* b0 = (const float*)d_in[9];
    const float* w1 = (const float*)d_in[10]; const float* b1 = (const float*)d_in[11];
    const float* w2 = (const float*)d_in[12]; const float* b2 = (const float*)d_in[13];
    const float* w3 = (const float*)d_in[14]; const float* b3 = (const float*)d_in[15];
    const float* w4 = (const float*)d_in[16]; const float* b4 = (const float*)d_in[17];
    float* out = (float*)d_out;

    char* ws = (char*)d_ws;
    size_t off = 0;
    auto carve = [&](size_t bytes) -> void* {
        void* p = ws + off;
        off += (bytes + 255) & ~(size_t)255;
        return p;
    };
    int*   row_ptr = (int*)  carve((NUM_TEAMS + 1) * sizeof(int));
    int*   bhist   = (int*)  carve(NBUCK * sizeof(int));
    int*   bbase   = (int*)  carve((NBUCK + 1) * sizeof(int));
    int*   bcursor = (int*)  carve(NBUCK * sizeof(int));
    int2*  recs    = (int2*) carve((size_t)N_EDGES * sizeof(int2));   // dead after P3
    int2*  epack   = (int2*) carve((size_t)N_EDGES * sizeof(int2));
    // alias dead recs (16MB): embedh (6.4) + x1h (6.4) + embed8 (3.2)
    __half* embedh = (__half*)recs;
    __half* x1h    = (__half*)recs + (size_t)NUM_TEAMS * EMBED;
    __hip_fp8x2_storage_t* embed8 =
        (__hip_fp8x2_storage_t*)((char*)recs + 2 * (size_t)NUM_TEAMS * EMBED * sizeof(__half));
    __half* x2h    = (__half*)carve((size_t)NUM_TEAMS * EMBED * sizeof(__half));
    __half* uv     = (__half*)carve((size_t)NUM_TEAMS * 16 * sizeof(__half));
    __hip_fp8x2_storage_t* x2_8 =
        (__hip_fp8x2_storage_t*)carve((size_t)NUM_TEAMS * 16 * sizeof(__hip_fp8x2_storage_t));
    __hip_fp8x2_storage_t* x1_8 =
        (__hip_fp8x2_storage_t*)carve((size_t)NUM_TEAMS * 16 * sizeof(__hip_fp8x2_storage_t));
    (void)ws_size; (void)in_sizes; (void)n_in; (void)out_size;

    const int conv_blocks = NUM_TEAMS / CONV_NPB;   // 6250 exact
    const int mlp_blocks  = (BQ + 255) / 256;
    const int cvt_pairs   = NUM_TEAMS * EMBED / 2;

    hipMemsetAsync(bhist, 0, NBUCK * sizeof(int), stream);
    bhist_kernel<<<P2_BLOCKS, 256, 0, stream>>>(dst, bhist, N_EDGES);
    bscan_kernel<<<1, 256, 0, stream>>>(bhist, bbase, bcursor, row_ptr);
    partition_kernel<<<P2_BLOCKS, 256, 0, stream>>>(src, dst, ew, bcursor, recs, N_EDGES);
    finalize_kernel<<<NBUCK, 256, 0, stream>>>(recs, bbase, row_ptr, epack);
    // recs dead -> overwrite with embedh/x1h/embed8
    cvt_kernel<<<(cvt_pairs + 255) / 256, 256, 0, stream>>>(embed, embedh, embed8, cvt_pairs);

    conv_kernel<<<conv_blocks, 256, 0, stream>>>(embedh, embed8, row_ptr, epack,
        w_rel + 0 * 1024, b_rel + 0 * 32, w_root + 0 * 1024,
        x2h, x2_8, nullptr, nullptr);
    conv_kernel<<<conv_blocks, 256, 0, stream>>>(x2h, x2_8, row_ptr, epack,
        w_rel + 1 * 1024, b_rel + 1 * 32, w_root + 1 * 1024,
        x1h, x1_8, nullptr, nullptr);
    conv_kernel<<<conv_blocks, 256, 0, stream>>>(x1h, x1_8, row_ptr, epack,
        w_rel + 2 * 1024, b_rel + 2 * 32, w_root + 2 * 1024,
        nullptr, nullptr, w0, uv);

    mlp_kernel<<<mlp_blocks, 256, 0, stream>>>(uv, home, away,
        b0, w1, b1, w2, b2, w3, b3, w4, b4, out, BQ);
}

// Round 10
// 276.050 us; speedup vs baseline: 1.2864x; 1.2864x over previous
//
#include <hip/hip_runtime.h>
#include <hip/hip_fp16.h>
#include <hip/hip_fp8.h>

#define NUM_TEAMS 100000
#define EMBED     32
#define N_EDGES   2000000
#define BQ        524288
#define TARGET_DIM 3

typedef __attribute__((ext_vector_type(2))) float f32x2;

// ---- fp8 e4m3 pack/unpack: HW builtins if present, class fallback otherwise ----
__device__ __forceinline__ f32x2 fp8x2_to_f32x2(unsigned short w) {
#if __has_builtin(__builtin_amdgcn_cvt_pk_f32_fp8)
    return __builtin_amdgcn_cvt_pk_f32_fp8((int)w, false);
#else
    __hip_fp8x2_e4m3 p; p.__x = (__hip_fp8x2_storage_t)w;
    float2 f = (float2)p;
    f32x2 r; r.x = f.x; r.y = f.y; return r;
#endif
}
__device__ __forceinline__ unsigned short f32x2_to_fp8x2(float a, float b) {
#if __has_builtin(__builtin_amdgcn_cvt_pk_fp8_f32)
    return (unsigned short)(__builtin_amdgcn_cvt_pk_fp8_f32(a, b, 0, false) & 0xffff);
#else
    __hip_fp8x2_e4m3 q(make_float2(a, b));
    return (unsigned short)q.__x;
#endif
}

// ---- bucket partition parameters ----
#define BSH    9
#define BSPAN  512
#define NBUCK  ((NUM_TEAMS + BSPAN - 1) / BSPAN)   // 196
#define TILE   8192
#define P2_BLOCKS ((N_EDGES + TILE - 1) / TILE)    // 245

// ---------------- P1: bucket histogram ----------------
__global__ void __launch_bounds__(256) bhist_kernel(const int* __restrict__ dst,
                                                    int* __restrict__ bhist, int n) {
    __shared__ int cnt[NBUCK];
    int t = threadIdx.x;
    for (int i = t; i < NBUCK; i += 256) cnt[i] = 0;
    __syncthreads();
    int base = blockIdx.x * TILE;
    for (int j = 0; j < TILE; j += 256) {
        int i = base + j + t;
        if (i < n) atomicAdd(&cnt[dst[i] >> BSH], 1);
    }
    __syncthreads();
    for (int i = t; i < NBUCK; i += 256) if (cnt[i]) atomicAdd(&bhist[i], cnt[i]);
}

// ---------------- P1b: scan bucket counts (1 block) ----------------
__global__ void __launch_bounds__(256) bscan_kernel(const int* __restrict__ bhist,
                                                    int* __restrict__ bbase,
                                                    int* __restrict__ bcursor,
                                                    int* __restrict__ row_ptr) {
    __shared__ int wsum[4];
    int t = threadIdx.x;
    int v = (t < NBUCK) ? bhist[t] : 0;
    int lane = t & 63, wid = t >> 6;
    int incl = v;
    #pragma unroll
    for (int off = 1; off < 64; off <<= 1) {
        int u = __shfl_up(incl, off, 64);
        if (lane >= off) incl += u;
    }
    if (lane == 63) wsum[wid] = incl;
    __syncthreads();
    int wofs = 0;
    for (int w = 0; w < wid; ++w) wofs += wsum[w];
    int excl = incl - v + wofs;
    if (t < NBUCK) { bbase[t] = excl; bcursor[t] = excl; }
    if (t == 0) { bbase[NBUCK] = N_EDGES; row_ptr[NUM_TEAMS] = N_EDGES; }
}

// ---------------- P2: chunked partition into bucket regions ----------------
__global__ void __launch_bounds__(256) partition_kernel(
        const int* __restrict__ src, const int* __restrict__ dst,
        const float* __restrict__ ew,
        int* __restrict__ bcursor, int2* __restrict__ recs, int n) {
    __shared__ int cnt[NBUCK];
    __shared__ int lbase[NBUCK];
    int t = threadIdx.x;
    for (int i = t; i < NBUCK; i += 256) cnt[i] = 0;
    __syncthreads();
    int base = blockIdx.x * TILE;
    for (int j = 0; j < TILE; j += 256) {
        int i = base + j + t;
        if (i < n) atomicAdd(&cnt[dst[i] >> BSH], 1);
    }
    __syncthreads();
    for (int b = t; b < NBUCK; b += 256) {
        int c = cnt[b];
        lbase[b] = c ? atomicAdd(&bcursor[b], c) : 0;
        cnt[b] = 0;
    }
    __syncthreads();
    for (int j = 0; j < TILE; j += 256) {
        int i = base + j + t;
        if (i < n) {
            int d = dst[i];
            int b = d >> BSH;
            int r = atomicAdd(&cnt[b], 1);
            int2 rec;
            rec.x = src[i] | ((d & (BSPAN - 1)) << 17);
            rec.y = __float_as_int(ew[i]);
            recs[lbase[b] + r] = rec;
        }
    }
}

// ---------------- P3: per-bucket CSR finalize ----------------
__global__ void __launch_bounds__(256) finalize_kernel(
        const int2* __restrict__ recs, const int* __restrict__ bbase,
        int* __restrict__ row_ptr, int2* __restrict__ epack) {
    __shared__ int cnt[BSPAN];
    __shared__ int excl[BSPAN];
    int b = blockIdx.x;
    int t = threadIdx.x;
    int rbase = bbase[b], rend = bbase[b + 1];
    for (int i = t; i < BSPAN; i += 256) cnt[i] = 0;
    __syncthreads();
    for (int k = rbase + t; k < rend; k += 256)
        atomicAdd(&cnt[recs[k].x >> 17], 1);
    __syncthreads();
    if (t < 64) {
        int c[8]; int s = 0;
        #pragma unroll
        for (int k = 0; k < 8; ++k) { c[k] = cnt[t * 8 + k]; s += c[k]; }
        int incl = s;
        #pragma unroll
        for (int off = 1; off < 64; off <<= 1) {
            int u = __shfl_up(incl, off, 64);
            if (t >= off) incl += u;
        }
        int e = incl - s;
        #pragma unroll
        for (int k = 0; k < 8; ++k) { excl[t * 8 + k] = e; e += c[k]; }
    }
    __syncthreads();
    for (int i = t; i < BSPAN; i += 256) {
        int node = b * BSPAN + i;
        if (node < NUM_TEAMS) row_ptr[node] = rbase + excl[i];
        cnt[i] = excl[i];
    }
    __syncthreads();
    for (int k = rbase + t; k < rend; k += 256) {
        int2 rec = recs[k];
        int dloc = rec.x >> 17;
        int r = atomicAdd(&cnt[dloc], 1);
        int2 e; e.x = rec.x & 0x1FFFF; e.y = rec.y;
        epack[rbase + r] = e;
    }
}

// ---------------- f32 -> fp16 + fp8 convert ----------------
__global__ void __launch_bounds__(256) cvt_kernel(const float* __restrict__ in,
                                                  __half* __restrict__ out16,
                                                  unsigned short* __restrict__ out8,
                                                  int n2) {
    int i = blockIdx.x * 256 + threadIdx.x;
    if (i < n2) {
        float2 v = *(const float2*)(in + 2 * i);
        *(__half2*)(out16 + 2 * i) = __floats2half2_rn(v.x, v.y);
        out8[i] = f32x2_to_fp8x2(v.x, v.y);
    }
}

// ---------------- fused GraphConv (16 lanes/node) ----------------
// Gather path: fp8-e4m3 table (3.2MB, L2-resident) + HW cvt_pk_f32_fp8, f32 acc.
#define CONV_NPB 16
__global__ void __launch_bounds__(256) conv_kernel(
        const __half* __restrict__ xh,                 // fp16 x (root path)
        const unsigned short* __restrict__ x8,         // fp8x2 x (gather), 16/node
        const int* __restrict__ row_ptr,
        const int2* __restrict__ epack,
        const float* __restrict__ w_rel,   // [32][32] row-major
        const float* __restrict__ b_rel,   // [32]
        const float* __restrict__ w_root,  // [32][32]
        __half* __restrict__ x_out,                    // nullable
        unsigned short* __restrict__ x8_out,           // nullable
        const float* __restrict__ w0,      // [8][64], nullable
        __half* __restrict__ uv_out) {     // [NUM_TEAMS][16], nullable
    __shared__ float s_wrelT[32 * 33];
    __shared__ float s_wrootT[32 * 33];
    __shared__ float s_b[32];
    __shared__ float s_agg[CONV_NPB][33];
    __shared__ float s_x[CONV_NPB][33];
    __shared__ float s_o[CONV_NPB][33];
    __shared__ float s_w0[8 * 66];

    int t = threadIdx.x;
    for (int i = t; i < 1024; i += 256) {
        int j = i >> 5, d = i & 31;
        s_wrelT[d * 33 + j]  = w_rel[i];
        s_wrootT[d * 33 + j] = w_root[i];
    }
    if (t < 32) s_b[t] = b_rel[t];
    if (w0) {
        for (int i = t; i < 512; i += 256)
            s_w0[(i >> 6) * 66 + (i & 63)] = w0[i];
    }

    int ln = t >> 4;           // node within block
    int l  = t & 15;           // dim-pair index
    int node = blockIdx.x * CONV_NPB + ln;   // 100000 = 6250*16 exact

    const __half2* xh2 = (const __half2*)xh;
    float2 xv = __half22float2(xh2[node * 16 + l]);
    int r0 = row_ptr[node], r1 = row_ptr[node + 1];
    int deg = r1 - r0;
    int kmain = r0 + (deg & ~7);

    f32x2 acc[8];
    #pragma unroll
    for (int j = 0; j < 8; ++j) { acc[j].x = 0.f; acc[j].y = 0.f; }

    for (int k = r0; k < kmain; k += 8) {
        int sx[8]; float wv[8];
        #pragma unroll
        for (int j = 0; j < 8; ++j) {
            long long raw = __builtin_nontemporal_load(
                                (const long long*)(epack + k + j));
            sx[j] = (int)(unsigned)(raw & 0xffffffffll);
            wv[j] = __int_as_float((int)(raw >> 32));
        }
        unsigned short r8[8];
        #pragma unroll
        for (int j = 0; j < 8; ++j) r8[j] = x8[sx[j] * 16 + l];
        #pragma unroll
        for (int j = 0; j < 8; ++j) {
            f32x2 g = fp8x2_to_f32x2(r8[j]);
            acc[j].x += wv[j] * g.x;
            acc[j].y += wv[j] * g.y;
        }
    }
    for (int k = kmain; k < r1; ++k) {
        long long raw = __builtin_nontemporal_load((const long long*)(epack + k));
        int   sxx = (int)(unsigned)(raw & 0xffffffffll);
        float wvv = __int_as_float((int)(raw >> 32));
        f32x2 g = fp8x2_to_f32x2(x8[sxx * 16 + l]);
        acc[0].x += wvv * g.x;
        acc[0].y += wvv * g.y;
    }
    float ax = ((acc[0].x + acc[1].x) + (acc[2].x + acc[3].x))
             + ((acc[4].x + acc[5].x) + (acc[6].x + acc[7].x));
    float ay = ((acc[0].y + acc[1].y) + (acc[2].y + acc[3].y))
             + ((acc[4].y + acc[5].y) + (acc[6].y + acc[7].y));

    s_agg[ln][2 * l]     = ax;
    s_agg[ln][2 * l + 1] = ay;
    s_x[ln][2 * l]       = xv.x;
    s_x[ln][2 * l + 1]   = xv.y;
    __syncthreads();

    int j0 = 2 * l, j1 = 2 * l + 1;
    float o0 = s_b[j0], o1 = s_b[j1];
    #pragma unroll
    for (int d = 0; d < 32; ++d) {
        float ag = s_agg[ln][d];
        float xx = s_x[ln][d];
        o0 += s_wrelT[d * 33 + j0] * ag + s_wrootT[d * 33 + j0] * xx;
        o1 += s_wrelT[d * 33 + j1] * ag + s_wrootT[d * 33 + j1] * xx;
    }
    o0 = (o0 >= 0.f) ? o0 : 0.01f * o0;
    o1 = (o1 >= 0.f) ? o1 : 0.01f * o1;
    if (x_out)
        ((__half2*)x_out)[node * 16 + l] = __floats2half2_rn(o0, o1);
    if (x8_out)
        x8_out[node * 16 + l] = f32x2_to_fp8x2(o0, o1);

    if (uv_out) {
        s_o[ln][2 * l]     = o0;
        s_o[ln][2 * l + 1] = o1;
        __syncthreads();
        const float* wrow = (l < 8) ? (s_w0 + l * 66) : (s_w0 + (l - 8) * 66 + 32);
        float uvv = 0.f;
        #pragma unroll
        for (int d = 0; d < 32; ++d) uvv += wrow[d] * s_o[ln][d];
        uv_out[node * 16 + l] = __float2half(uvv);
    }
}

// ---------------- final pair MLP (layers 1-4) + log_softmax ----------------
__global__ void __launch_bounds__(256) mlp_kernel(
        const __half* __restrict__ uv,
        const int* __restrict__ home, const int* __restrict__ away,
        const float* __restrict__ b0,
        const float* __restrict__ w1, const float* __restrict__ b1,
        const float* __restrict__ w2, const float* __restrict__ b2,
        const float* __restrict__ w3, const float* __restrict__ b3,
        const float* __restrict__ w4, const float* __restrict__ b4,
        float* __restrict__ out, int n) {
    __shared__ float s_w1[64], s_w2[64], s_w3[64], s_w4[24];
    __shared__ float s_b0[8], s_b1[8], s_b2[8], s_b3[8], s_b4[3];
    int t = threadIdx.x;
    if (t < 64) { s_w1[t] = w1[t]; s_w2[t] = w2[t]; s_w3[t] = w3[t]; }
    if (t < 24) s_w4[t] = w4[t];
    if (t < 8)  { s_b0[t] = b0[t]; s_b1[t] = b1[t]; s_b2[t] = b2[t]; s_b3[t] = b3[t]; }
    if (t < 3)  s_b4[t] = b4[t];
    __syncthreads();

    int i = blockIdx.x * 256 + t;
    if (i >= n) return;

    int hi = __builtin_nontemporal_load(home + i);
    int ai = __builtin_nontemporal_load(away + i);

    const __half2* pu = (const __half2*)(uv + (size_t)hi * 16);
    const __half2* pv = (const __half2*)(uv + (size_t)ai * 16 + 8);

    float h1[8];
    #pragma unroll
    for (int q = 0; q < 4; ++q) {
        float2 fu = __half22float2(pu[q]);
        float2 fv = __half22float2(pv[q]);
        float o0 = fu.x + fv.x + s_b0[2 * q];
        float o1 = fu.y + fv.y + s_b0[2 * q + 1];
        h1[2 * q]     = (o0 >= 0.f) ? o0 : 0.01f * o0;
        h1[2 * q + 1] = (o1 >= 0.f) ? o1 : 0.01f * o1;
    }

    float h2[8];
    #pragma unroll
    for (int j = 0; j < 8; ++j) {
        float o = s_b1[j];
        #pragma unroll
        for (int d = 0; d < 8; ++d) o += s_w1[j * 8 + d] * h1[d];
        h2[j] = (o >= 0.f) ? o : 0.01f * o;
    }
    float h3[8];
    #pragma unroll
    for (int j = 0; j < 8; ++j) {
        float o = s_b2[j];
        #pragma unroll
        for (int d = 0; d < 8; ++d) o += s_w2[j * 8 + d] * h2[d];
        h3[j] = (o >= 0.f) ? o : 0.01f * o;
    }
    float h4[8];
    #pragma unroll
    for (int j = 0; j < 8; ++j) {
        float o = s_b3[j];
        #pragma unroll
        for (int d = 0; d < 8; ++d) o += s_w3[j * 8 + d] * h3[d];
        h4[j] = (o >= 0.f) ? o : 0.01f * o;
    }
    float f[3];
    #pragma unroll
    for (int j = 0; j < 3; ++j) {
        float o = s_b4[j];
        #pragma unroll
        for (int d = 0; d < 8; ++d) o += s_w4[j * 8 + d] * h4[d];
        f[j] = (o >= 0.f) ? o : 0.01f * o;
    }
    float m  = fmaxf(f[0], fmaxf(f[1], f[2]));
    float s  = expf(f[0] - m) + expf(f[1] - m) + expf(f[2] - m);
    float ls = logf(s);
    out[3 * i + 0] = f[0] - m - ls;
    out[3 * i + 1] = f[1] - m - ls;
    out[3 * i + 2] = f[2] - m - ls;
}

// ---------------- launch ----------------

extern "C" void kernel_launch(void* const* d_in, const int* in_sizes, int n_in,
                              void* d_out, int out_size, void* d_ws, size_t ws_size,
                              hipStream_t stream) {
    const int*   edge_index = (const int*)d_in[0];
    const int*   src   = edge_index;
    const int*   dst   = edge_index + N_EDGES;
    const float* ew    = (const float*)d_in[1];
    const int*   home  = (const int*)d_in[2];
    const int*   away  = (const int*)d_in[3];
    const float* embed = (const float*)d_in[4];
    const float* w_rel  = (const float*)d_in[5];
    const float* b_rel  = (const float*)d_in[6];
    const float* w_root = (const float*)d_in[7];
    const float* w0 = (const float*)d_in[8];  const float* b0 = (const float*)d_in[9];
    const float* w1 = (const float*)d_in[10]; const float* b1 = (const float*)d_in[11];
    const float* w2 = (const float*)d_in[12]; const float* b2 = (const float*)d_in[13];
    const float* w3 = (const float*)d_in[14]; const float* b3 = (const float*)d_in[15];
    const float* w4 = (const float*)d_in[16]; const float* b4 = (const float*)d_in[17];
    float* out = (float*)d_out;

    char* ws = (char*)d_ws;
    size_t off = 0;
    auto carve = [&](size_t bytes) -> void* {
        void* p = ws + off;
        off += (bytes + 255) & ~(size_t)255;
        return p;
    };
    int*   row_ptr = (int*)  carve((NUM_TEAMS + 1) * sizeof(int));
    int*   bhist   = (int*)  carve(NBUCK * sizeof(int));
    int*   bbase   = (int*)  carve((NBUCK + 1) * sizeof(int));
    int*   bcursor = (int*)  carve(NBUCK * sizeof(int));
    int2*  recs    = (int2*) carve((size_t)N_EDGES * sizeof(int2));   // dead after P3
    int2*  epack   = (int2*) carve((size_t)N_EDGES * sizeof(int2));
    // alias dead recs (16MB): embedh (6.4) + x1h (6.4) + embed8 (3.2)
    __half* embedh = (__half*)recs;
    __half* x1h    = (__half*)recs + (size_t)NUM_TEAMS * EMBED;
    unsigned short* embed8 =
        (unsigned short*)((char*)recs + 2 * (size_t)NUM_TEAMS * EMBED * sizeof(__half));
    __half* x2h    = (__half*)carve((size_t)NUM_TEAMS * EMBED * sizeof(__half));
    __half* uv     = (__half*)carve((size_t)NUM_TEAMS * 16 * sizeof(__half));
    unsigned short* x2_8 =
        (unsigned short*)carve((size_t)NUM_TEAMS * 16 * sizeof(unsigned short));
    unsigned short* x1_8 =
        (unsigned short*)carve((size_t)NUM_TEAMS * 16 * sizeof(unsigned short));
    (void)ws_size; (void)in_sizes; (void)n_in; (void)out_size;

    const int conv_blocks = NUM_TEAMS / CONV_NPB;   // 6250 exact
    const int mlp_blocks  = (BQ + 255) / 256;
    const int cvt_pairs   = NUM_TEAMS * EMBED / 2;

    hipMemsetAsync(bhist, 0, NBUCK * sizeof(int), stream);
    bhist_kernel<<<P2_BLOCKS, 256, 0, stream>>>(dst, bhist, N_EDGES);
    bscan_kernel<<<1, 256, 0, stream>>>(bhist, bbase, bcursor, row_ptr);
    partition_kernel<<<P2_BLOCKS, 256, 0, stream>>>(src, dst, ew, bcursor, recs, N_EDGES);
    finalize_kernel<<<NBUCK, 256, 0, stream>>>(recs, bbase, row_ptr, epack);
    // recs dead -> overwrite with embedh/x1h/embed8
    cvt_kernel<<<(cvt_pairs + 255) / 256, 256, 0, stream>>>(embed, embedh, embed8, cvt_pairs);

    conv_kernel<<<conv_blocks, 256, 0, stream>>>(embedh, embed8, row_ptr, epack,
        w_rel + 0 * 1024, b_rel + 0 * 32, w_root + 0 * 1024,
        x2h, x2_8, nullptr, nullptr);
    conv_kernel<<<conv_blocks, 256, 0, stream>>>(x2h, x2_8, row_ptr, epack,
        w_rel + 1 * 1024, b_rel + 1 * 32, w_root + 1 * 1024,
        x1h, x1_8, nullptr, nullptr);
    conv_kernel<<<conv_blocks, 256, 0, stream>>>(x1h, x1_8, row_ptr, epack,
        w_rel + 2 * 1024, b_rel + 2 * 32, w_root + 2 * 1024,
        nullptr, nullptr, w0, uv);

    mlp_kernel<<<mlp_blocks, 256, 0, stream>>>(uv, home, away,
        b0, w1, b1, w2, b2, w3, b3, w4, b4, out, BQ);
}